// Round 16
// baseline (1932.005 us; speedup 1.0000x reference)
//
#include <hip/hip_runtime.h>

// MULTI-VARIANT DIAGNOSTIC: four double-pass kernels, each its own dispatch
// (~400-550us, all above the ~338us fill cutoff) -> per-variant rocprof rows.
//   A: production  (NT ld/st, 64-lane rows, 12 shfl / 2 rows)  pass0 -> d_out
//   B: plain ld/st (else identical to A)                        -> ws
//   C: 32-lane rows, 5 shfl / 2 rows                            -> ws
//   D: no-reduce stream control (no shuffles at all)            -> ws
// Next round picks the winner as the single production kernel.

#define D_CH 256
#define N_F  256
#define ROWS_TOTAL 2048
#define CHUNKS 16
#define ROWS_PER_BLOCK (ROWS_TOTAL / CHUNKS)   // 128

typedef float f32x4 __attribute__((ext_vector_type(4)));

// ---------- variant A: production (NT), double-pass ----------
__global__ __launch_bounds__(256) void diag_A_nt(
    const float* __restrict__ x, const float* __restrict__ W,
    const float* __restrict__ bias, const int* __restrict__ perm,
    float* __restrict__ o0, float* __restrict__ o1)
{
    __shared__ float wp[N_F];
    const int d = blockIdx.x, chunk = blockIdx.y, tid = threadIdx.x;
    wp[perm[d * N_F + tid]] = W[d * N_F + tid];
    __syncthreads();
    const int lane = tid & 63, wave = tid >> 6;
    const f32x4 w4 = *reinterpret_cast<const f32x4*>(&wp[lane * 4]);
    const float bv = bias[d];
    const int row0 = chunk * ROWS_PER_BLOCK + wave;
    const size_t rs4 = (size_t)4 * D_CH * N_F;

    for (int pass = 0; pass < 2; ++pass) {
        float* o = pass ? o1 : o0;
        for (int i = 0; i < 32; i += 2) {
            const size_t b0 = ((size_t)(row0 + 4 * i) * D_CH + d) * N_F + lane * 4;
            const size_t b1 = b0 + rs4;
            const f32x4 a0 = __builtin_nontemporal_load(reinterpret_cast<const f32x4*>(x + b0));
            const f32x4 a1 = __builtin_nontemporal_load(reinterpret_cast<const f32x4*>(x + b1));
            float p0 = a0.x * w4.x + a0.y * w4.y + a0.z * w4.z + a0.w * w4.w;
            float p1 = a1.x * w4.x + a1.y * w4.y + a1.z * w4.z + a1.w * w4.w;
            #pragma unroll
            for (int m = 32; m >= 1; m >>= 1) {
                p0 += __shfl_xor(p0, m, 64);
                p1 += __shfl_xor(p1, m, 64);
            }
            const float y0 = p0 + bv, y1 = p1 + bv;
            f32x4 v0; v0.x = v0.y = v0.z = v0.w = y0;
            f32x4 v1; v1.x = v1.y = v1.z = v1.w = y1;
            __builtin_nontemporal_store(v0, reinterpret_cast<f32x4*>(o + b0));
            __builtin_nontemporal_store(v1, reinterpret_cast<f32x4*>(o + b1));
        }
    }
}

// ---------- variant B: plain loads/stores ----------
__global__ __launch_bounds__(256) void diag_B_plain(
    const float* __restrict__ x, const float* __restrict__ W,
    const float* __restrict__ bias, const int* __restrict__ perm,
    float* __restrict__ o0, float* __restrict__ o1)
{
    __shared__ float wp[N_F];
    const int d = blockIdx.x, chunk = blockIdx.y, tid = threadIdx.x;
    wp[perm[d * N_F + tid]] = W[d * N_F + tid];
    __syncthreads();
    const int lane = tid & 63, wave = tid >> 6;
    const f32x4 w4 = *reinterpret_cast<const f32x4*>(&wp[lane * 4]);
    const float bv = bias[d];
    const int row0 = chunk * ROWS_PER_BLOCK + wave;
    const size_t rs4 = (size_t)4 * D_CH * N_F;

    for (int pass = 0; pass < 2; ++pass) {
        float* o = pass ? o1 : o0;
        for (int i = 0; i < 32; i += 2) {
            const size_t b0 = ((size_t)(row0 + 4 * i) * D_CH + d) * N_F + lane * 4;
            const size_t b1 = b0 + rs4;
            const f32x4 a0 = *reinterpret_cast<const f32x4*>(x + b0);
            const f32x4 a1 = *reinterpret_cast<const f32x4*>(x + b1);
            float p0 = a0.x * w4.x + a0.y * w4.y + a0.z * w4.z + a0.w * w4.w;
            float p1 = a1.x * w4.x + a1.y * w4.y + a1.z * w4.z + a1.w * w4.w;
            #pragma unroll
            for (int m = 32; m >= 1; m >>= 1) {
                p0 += __shfl_xor(p0, m, 64);
                p1 += __shfl_xor(p1, m, 64);
            }
            const float y0 = p0 + bv, y1 = p1 + bv;
            f32x4 v0; v0.x = v0.y = v0.z = v0.w = y0;
            f32x4 v1; v1.x = v1.y = v1.z = v1.w = y1;
            *reinterpret_cast<f32x4*>(o + b0) = v0;
            *reinterpret_cast<f32x4*>(o + b1) = v1;
        }
    }
}

// ---------- variant C: 32-lane rows, 5 shuffles per 2 rows ----------
__global__ __launch_bounds__(256) void diag_C_half(
    const float* __restrict__ x, const float* __restrict__ W,
    const float* __restrict__ bias, const int* __restrict__ perm,
    float* __restrict__ o0, float* __restrict__ o1)
{
    __shared__ float wp[N_F];
    const int d = blockIdx.x, chunk = blockIdx.y, tid = threadIdx.x;
    wp[perm[d * N_F + tid]] = W[d * N_F + tid];
    __syncthreads();
    const int lane = tid & 63, wave = tid >> 6;
    const int lane32 = lane & 31, half = lane >> 5;
    const f32x4 wlo = *reinterpret_cast<const f32x4*>(&wp[lane32 * 8]);
    const f32x4 whi = *reinterpret_cast<const f32x4*>(&wp[lane32 * 8 + 4]);
    const float bv = bias[d];
    const int row0 = chunk * ROWS_PER_BLOCK + wave;

    for (int pass = 0; pass < 2; ++pass) {
        float* o = pass ? o1 : o0;
        for (int i = 0; i < 16; ++i) {
            // wave's 32 rows are row0 + 4*j, j=0..31; this iter: j = 2i+half
            const int r = row0 + 4 * (2 * i + half);
            const size_t b = ((size_t)r * D_CH + d) * N_F + lane32 * 8;
            const f32x4 a0 = *reinterpret_cast<const f32x4*>(x + b);
            const f32x4 a1 = *reinterpret_cast<const f32x4*>(x + b + 4);
            float p = a0.x * wlo.x + a0.y * wlo.y + a0.z * wlo.z + a0.w * wlo.w
                    + a1.x * whi.x + a1.y * whi.y + a1.z * whi.z + a1.w * whi.w;
            #pragma unroll
            for (int m = 16; m >= 1; m >>= 1)
                p += __shfl_xor(p, m, 64);   // stays within each 32-lane half
            const float y = p + bv;
            f32x4 v; v.x = v.y = v.z = v.w = y;
            *reinterpret_cast<f32x4*>(o + b)     = v;
            *reinterpret_cast<f32x4*>(o + b + 4) = v;
        }
    }
}

// ---------- variant D: stream control (no reduction) ----------
__global__ __launch_bounds__(256) void diag_D_stream(
    const float* __restrict__ x, const float* __restrict__ W,
    const float* __restrict__ bias, const int* __restrict__ perm,
    float* __restrict__ o0, float* __restrict__ o1)
{
    __shared__ float wp[N_F];
    const int d = blockIdx.x, chunk = blockIdx.y, tid = threadIdx.x;
    wp[perm[d * N_F + tid]] = W[d * N_F + tid];
    __syncthreads();
    const int lane = tid & 63, wave = tid >> 6;
    const f32x4 w4 = *reinterpret_cast<const f32x4*>(&wp[lane * 4]);
    const int row0 = chunk * ROWS_PER_BLOCK + wave;
    const size_t rs4 = (size_t)4 * D_CH * N_F;

    for (int pass = 0; pass < 2; ++pass) {
        float* o = pass ? o1 : o0;
        for (int i = 0; i < 32; i += 2) {
            const size_t b0 = ((size_t)(row0 + 4 * i) * D_CH + d) * N_F + lane * 4;
            const size_t b1 = b0 + rs4;
            const f32x4 a0 = *reinterpret_cast<const f32x4*>(x + b0);
            const f32x4 a1 = *reinterpret_cast<const f32x4*>(x + b1);
            *reinterpret_cast<f32x4*>(o + b0) = a0 * w4;   // dependent on load; no reduce
            *reinterpret_cast<f32x4*>(o + b1) = a1 * w4;
        }
    }
}

extern "C" void kernel_launch(void* const* d_in, const int* in_sizes, int n_in,
                              void* d_out, int out_size, void* d_ws, size_t ws_size,
                              hipStream_t stream) {
    const float* x    = (const float*)d_in[0];
    const float* W    = (const float*)d_in[1];
    const float* bias = (const float*)d_in[2];
    const int*   perm = (const int*)d_in[3];
    float*       out  = (float*)d_out;
    float*       ws   = (float*)d_ws;

    const size_t region = (size_t)ROWS_TOTAL * D_CH * N_F;        // 2^27 floats = 512 MiB
    dim3 grid(D_CH, CHUNKS);

    if (ws_size >= 4 * region * sizeof(float)) {
        // Full diagnostic: distinct 512 MiB ws regions per variant.
        diag_A_nt    <<<grid, 256, 0, stream>>>(x, W, bias, perm, out, ws);
        diag_B_plain <<<grid, 256, 0, stream>>>(x, W, bias, perm, ws + region,     ws + region);
        diag_C_half  <<<grid, 256, 0, stream>>>(x, W, bias, perm, ws + 2 * region, ws + 2 * region);
        diag_D_stream<<<grid, 256, 0, stream>>>(x, W, bias, perm, ws + 3 * region, ws + 3 * region);
    } else if (ws_size >= region * sizeof(float)) {
        diag_A_nt    <<<grid, 256, 0, stream>>>(x, W, bias, perm, out, ws);
        diag_B_plain <<<grid, 256, 0, stream>>>(x, W, bias, perm, ws, ws);
        diag_C_half  <<<grid, 256, 0, stream>>>(x, W, bias, perm, ws, ws);
        diag_D_stream<<<grid, 256, 0, stream>>>(x, W, bias, perm, ws, ws);
    } else {
        // Safe fallback: double-pass into out (idempotent), still profiled.
        diag_A_nt    <<<grid, 256, 0, stream>>>(x, W, bias, perm, out, out);
    }
}